// Round 8
// baseline (412.506 us; speedup 1.0000x reference)
//
#include <hip/hip_runtime.h>
#include <hip/hip_bf16.h>

typedef __bf16 bf16_t;
typedef __bf16 bf16x8 __attribute__((ext_vector_type(8)));
typedef float f32x4 __attribute__((ext_vector_type(4)));

#define NB 16384
#define NSPLIT 16           // col groups for logits kernel
#define CG (NB / NSPLIT)    // 1024 cols per block
#define BNT 64              // cols per B-subtile
#define NT (CG / BNT)       // 16 B-subtiles per block

__device__ inline bf16x8 ld8(const bf16_t* p) { return *(const bf16x8*)p; }

// direct global->LDS async copy, 16 B/lane (wave-uniform LDS base + lane*16)
__device__ inline void gload_lds16(const bf16_t* g, bf16_t* l) {
  __builtin_amdgcn_global_load_lds(
      (const __attribute__((address_space(1))) unsigned int*)g,
      (__attribute__((address_space(3))) unsigned int*)l, 16, 0, 0);
}

// ---------------------------------------------------------------------------
// K0 "prep": grid sections (boundaries via nimg/nnum so host can skip big
// conversions when workspace is small).
//  [0,nimg):                 img fp32 -> bf16 CHUNK-SWIZZLED (k ^ ((row&7)<<3))
//  [nimg,nimg+nnum):         num fp32 -> bf16 swizzled
//  [.., ..+1280):            4 weight transposes fp32 [K][128] -> bf16 [128][K] swizzled
//  last block:               zero lossacc + counter
// ---------------------------------------------------------------------------
__global__ void prep(const float* __restrict__ img, const float* __restrict__ num,
                     const float* __restrict__ Wi1, const float* __restrict__ Wn1,
                     const float* __restrict__ Wi2, const float* __restrict__ Wn2,
                     bf16_t* __restrict__ imgb, bf16_t* __restrict__ numb,
                     bf16_t* __restrict__ Wi1t, bf16_t* __restrict__ Wn1t,
                     bf16_t* __restrict__ Wi2t, bf16_t* __restrict__ Wn2t,
                     float* __restrict__ lossacc, int nimg, int nnum) {
  int b = blockIdx.x;
  if (b < nimg) {                      // img: 33.55M elements, 8192/block
    int base = b * 8192;
#pragma unroll
    for (int i = 0; i < 4; i++) {
      int e = base + (threadIdx.x + i * 256) * 8;
      int row = e >> 11, k = e & 2047;
      float4 f0 = *(const float4*)(img + e);
      float4 f1 = *(const float4*)(img + e + 4);
      bf16x8 v;
      v[0]=(bf16_t)f0.x; v[1]=(bf16_t)f0.y; v[2]=(bf16_t)f0.z; v[3]=(bf16_t)f0.w;
      v[4]=(bf16_t)f1.x; v[5]=(bf16_t)f1.y; v[6]=(bf16_t)f1.z; v[7]=(bf16_t)f1.w;
      *(bf16x8*)(imgb + (size_t)row * 2048 + (k ^ ((row & 7) << 3))) = v;
    }
    return;
  }
  b -= nimg;
  if (b < nnum) {                      // num: 4.19M elements
    int base = b * 8192;
#pragma unroll
    for (int i = 0; i < 4; i++) {
      int e = base + (threadIdx.x + i * 256) * 8;
      int row = e >> 8, k = e & 255;
      float4 f0 = *(const float4*)(num + e);
      float4 f1 = *(const float4*)(num + e + 4);
      bf16x8 v;
      v[0]=(bf16_t)f0.x; v[1]=(bf16_t)f0.y; v[2]=(bf16_t)f0.z; v[3]=(bf16_t)f0.w;
      v[4]=(bf16_t)f1.x; v[5]=(bf16_t)f1.y; v[6]=(bf16_t)f1.z; v[7]=(bf16_t)f1.w;
      *(bf16x8*)(numb + (size_t)row * 256 + (k ^ ((row & 7) << 3))) = v;
    }
    return;
  }
  b -= nnum;
  if (b < 1280) {                      // weight transposes + swizzle
    int idx = b * 256 + threadIdx.x;
    if (idx < 262144) { int k = idx >> 7, n = idx & 127;
      Wi1t[n * 2048 + (k ^ ((n & 7) << 3))] = (bf16_t)Wi1[idx]; return; }
    idx -= 262144;
    if (idx < 32768) { int k = idx >> 7, n = idx & 127;
      Wn1t[n * 256 + (k ^ ((n & 7) << 3))] = (bf16_t)Wn1[idx]; return; }
    idx -= 32768;
    if (idx < 16384) { int k = idx >> 7, n = idx & 127;
      Wi2t[n * 128 + (k ^ ((n & 7) << 3))] = (bf16_t)Wi2[idx]; return; }
    idx -= 16384;
    { int k = idx >> 7, n = idx & 127;
      Wn2t[n * 128 + (k ^ ((n & 7) << 3))] = (bf16_t)Wn2[idx]; }
  } else {
    if (threadIdx.x < 2) lossacc[threadIdx.x] = 0.f;   // loss acc + counter
  }
}

// ---------------------------------------------------------------------------
// K1: FUSED mlp1+relu+mlp2+l2norm. Blocks 0..511 img (K=2048), 512..1023 num
// (K=256). BM=32. PRE=true: A staged via global_load_lds from pre-swizzled
// bf16. PRE=false: A staged from fp32 with VGPR convert + swizzled ds_write
// (17.9MB-workspace fallback). Weights always pre-swizzled + gload_lds.
// H never leaves the block (LDS). Out stored chunk-swizzled per row.
// LDS = 8K + 32K = 40KB -> 4 blocks/CU.
// ---------------------------------------------------------------------------
template <bool PRE>
__global__ __launch_bounds__(256, 4) void mlp_fused(
    const bf16_t* __restrict__ imgb, const bf16_t* __restrict__ numb,
    const float* __restrict__ imgf, const float* __restrict__ numf,
    const bf16_t* __restrict__ Wi1t, const bf16_t* __restrict__ Wn1t,
    const bf16_t* __restrict__ Wi2t, const bf16_t* __restrict__ Wn2t,
    const float* __restrict__ bi1, const float* __restrict__ bn1,
    const float* __restrict__ bi2, const float* __restrict__ bn2,
    bf16_t* __restrict__ ipb, bf16_t* __restrict__ npb) {
  __shared__ bf16_t As[32 * 128];
  __shared__ bf16_t Bs[128 * 128];
  __shared__ float rnorm[32];
  const int bid = blockIdx.x;
  const bool isnum = bid >= 512;
  const bf16_t* Xb = isnum ? numb : imgb;
  const float*  Xf = isnum ? numf : imgf;
  const bf16_t* W1 = isnum ? Wn1t : Wi1t;
  const bf16_t* W2 = isnum ? Wn2t : Wi2t;
  const float* b1  = isnum ? bn1 : bi1;
  const float* b2  = isnum ? bn2 : bi2;
  bf16_t* Out = isnum ? npb : ipb;
  const int K = isnum ? 256 : 2048;
  const int t = threadIdx.x, l = t & 63, wid = t >> 6;
  const int wm = wid >> 1, wn = wid & 1;      // wave tile 16 rows x 64 cols
  const int row0 = (bid & 511) * 32;
  if (t < 32) rnorm[t] = 0.f;

  f32x4 acc[4];
#pragma unroll
  for (int j = 0; j < 4; j++) acc[j] = (f32x4){0.f, 0.f, 0.f, 0.f};

  for (int k0 = 0; k0 < K; k0 += 128) {
    __syncthreads();
    // stage A (8KB): 512 chunk-slots
#pragma unroll
    for (int i = 0; i < 2; i++) {
      int s = t + i * 256;
      if constexpr (PRE) {
        gload_lds16(Xb + (size_t)(row0 + (s >> 4)) * K + k0 + (s & 15) * 8, As + s * 8);
      } else {
        int r = s >> 4, c = s & 15;
        const float* src = Xf + (size_t)(row0 + r) * K + k0 + c * 8;
        float4 f0 = *(const float4*)(src);
        float4 f1 = *(const float4*)(src + 4);
        bf16x8 v;
        v[0]=(bf16_t)f0.x; v[1]=(bf16_t)f0.y; v[2]=(bf16_t)f0.z; v[3]=(bf16_t)f0.w;
        v[4]=(bf16_t)f1.x; v[5]=(bf16_t)f1.y; v[6]=(bf16_t)f1.z; v[7]=(bf16_t)f1.w;
        *(bf16x8*)(As + r * 128 + ((c ^ (r & 7)) << 3)) = v;
      }
    }
    // stage B (32KB): 2048 chunk-slots, linear dest (source pre-swizzled)
#pragma unroll
    for (int i = 0; i < 8; i++) {
      int s = t + i * 256;
      gload_lds16(W1 + (size_t)(s >> 4) * K + k0 + (s & 15) * 8, Bs + s * 8);
    }
    __syncthreads();
#pragma unroll
    for (int ks = 0; ks < 4; ks++) {
      int r = wm * 16 + (l & 15);
      int c = ks * 4 + (l >> 4);
      bf16x8 a = ld8(As + r * 128 + ((c ^ (r & 7)) << 3));
#pragma unroll
      for (int nt = 0; nt < 4; nt++) {
        int rb = wn * 64 + nt * 16 + (l & 15);
        bf16x8 bfr = ld8(Bs + rb * 128 + ((c ^ (rb & 7)) << 3));
        acc[nt] = __builtin_amdgcn_mfma_f32_16x16x32_bf16(a, bfr, acc[nt], 0, 0, 0);
      }
    }
  }
  __syncthreads();   // phase-1 LDS reads complete
  // H = relu(acc + b1) -> As, chunk-swizzled by local row
  {
    int rbase = wm * 16 + ((l >> 4) << 2);
#pragma unroll
    for (int nt = 0; nt < 4; nt++) {
      int col = wn * 64 + nt * 16 + (l & 15);
      float bv = b1[col];
#pragma unroll
      for (int r4 = 0; r4 < 4; r4++) {
        int row = rbase + r4;
        float h = fmaxf(acc[nt][r4] + bv, 0.f);
        As[row * 128 + (col ^ ((row & 7) << 3))] = (bf16_t)h;
      }
    }
  }
  // stage W2 (pre-swizzled) into Bs
#pragma unroll
  for (int i = 0; i < 8; i++) {
    int s = t + i * 256;
    gload_lds16(W2 + (size_t)(s >> 4) * 128 + (s & 15) * 8, Bs + s * 8);
  }
  __syncthreads();   // drains H ds_writes + W2 gloads
  f32x4 acc2[4];
#pragma unroll
  for (int j = 0; j < 4; j++) acc2[j] = (f32x4){0.f, 0.f, 0.f, 0.f};
#pragma unroll
  for (int ks = 0; ks < 4; ks++) {
    int r = wm * 16 + (l & 15);
    int c = ks * 4 + (l >> 4);
    bf16x8 a = ld8(As + r * 128 + ((c ^ (r & 7)) << 3));
#pragma unroll
    for (int nt = 0; nt < 4; nt++) {
      int rb = wn * 64 + nt * 16 + (l & 15);
      bf16x8 bfr = ld8(Bs + rb * 128 + ((c ^ (rb & 7)) << 3));
      acc2[nt] = __builtin_amdgcn_mfma_f32_16x16x32_bf16(a, bfr, acc2[nt], 0, 0, 0);
    }
  }
  // + bias, l2norm, swizzled store
  float vv[4][4];
#pragma unroll
  for (int nt = 0; nt < 4; nt++) {
    int col = wn * 64 + nt * 16 + (l & 15);
    float bv = b2[col];
#pragma unroll
    for (int r4 = 0; r4 < 4; r4++) vv[nt][r4] = acc2[nt][r4] + bv;
  }
#pragma unroll
  for (int r4 = 0; r4 < 4; r4++) {
    float p = 0.f;
#pragma unroll
    for (int nt = 0; nt < 4; nt++) p += vv[nt][r4] * vv[nt][r4];
    p += __shfl_xor(p, 1); p += __shfl_xor(p, 2);
    p += __shfl_xor(p, 4); p += __shfl_xor(p, 8);
    if ((l & 15) == 0) atomicAdd(&rnorm[wm * 16 + ((l >> 4) << 2) + r4], p);
  }
  __syncthreads();
#pragma unroll
  for (int r4 = 0; r4 < 4; r4++) {
    int rl = wm * 16 + ((l >> 4) << 2) + r4;
    float sc = 1.f / fmaxf(sqrtf(rnorm[rl]), 1e-12f);
#pragma unroll
    for (int nt = 0; nt < 4; nt++) {
      int col = wn * 64 + nt * 16 + (l & 15);
      int swcol = col ^ ((rl & 7) << 3);
      Out[(size_t)(row0 + rl) * 128 + swcol] = (bf16_t)(vv[nt][r4] * sc);
    }
  }
}

// ---------------------------------------------------------------------------
// K2 logits v3: 512 threads / 8 waves (4 wm x 2 wn, 32x32 per wave).
// Block (bm,g): rows [bm*128,+128) x cols [g*1024,+1024) in 16 subtiles of 64.
// A-frags in registers; 32KB LDS double-buffers B; col sums via LDS atomics.
// LDS ~38KB, target 3 blocks/CU = 24 waves (vs 12 before).
// ---------------------------------------------------------------------------
__global__ __launch_bounds__(512, 6) void logits_split(
    const bf16_t* __restrict__ IP, const bf16_t* __restrict__ NP,
    const float* __restrict__ log_temp, float* __restrict__ rowpart,
    float* __restrict__ colpart, float* __restrict__ diag) {
  __shared__ bf16_t BsAll[2 * BNT * 128];  // 32 KB: A staging, then B dbuf
  __shared__ float colred[CG];             // 4 KB, LDS-atomic accumulated
  __shared__ float rowred[2][128];         // 1 KB
  int bid = blockIdx.x;
  int sw = (bid & 7) * (128 * NSPLIT / 8) + (bid >> 3);  // XCD-chunked bijective
  int bm = sw >> 4, g = sw & (NSPLIT - 1);
  const int t = threadIdx.x, l = t & 63, wid = t >> 6;
  const int wm = wid >> 1, wn = wid & 1;   // wave tile 32 rows x 32 cols
  const float invt = __expf(-log_temp[0]);
  const float kk = invt * 1.44269504088896f;   // log2(e)/t

  for (int i = t; i < CG; i += 512) colred[i] = 0.f;
  // stage A (128x128, 32KB) into BsAll; lift frags to regs
#pragma unroll
  for (int i = 0; i < 4; i++) {
    int s = t + i * 512;
    gload_lds16(IP + (size_t)bm * (128 * 128) + s * 8, BsAll + s * 8);
  }
  __syncthreads();
  bf16x8 af[2][4];                          // [mt][ks], 32 VGPR
#pragma unroll
  for (int mt = 0; mt < 2; mt++) {
    int r = wm * 32 + mt * 16 + (l & 15);
#pragma unroll
    for (int ks = 0; ks < 4; ks++) {
      int c = ks * 4 + (l >> 4);
      af[mt][ks] = ld8(BsAll + r * 128 + ((c ^ (r & 7)) << 3));
    }
  }
  __syncthreads();                          // all waves done reading A
#pragma unroll
  for (int i = 0; i < 2; i++) {             // stage B tile 0 into half 0
    int s = t + i * 512;
    gload_lds16(NP + (size_t)(g * CG) * 128 + s * 8, BsAll + s * 8);
  }
  __syncthreads();                          // drains vmcnt: B0 ready

  f32x4 racc[2];
  racc[0] = (f32x4){0.f, 0.f, 0.f, 0.f};
  racc[1] = (f32x4){0.f, 0.f, 0.f, 0.f};

#pragma unroll 1
  for (int tl = 0; tl < NT; tl++) {
    bf16_t* Bsc = BsAll + (tl & 1) * (BNT * 128);
    if (tl + 1 < NT) {                      // async-stage next tile, other half
      bf16_t* Bsn = BsAll + ((tl + 1) & 1) * (BNT * 128);
      const bf16_t* src = NP + (size_t)(g * CG + (tl + 1) * BNT) * 128;
#pragma unroll
      for (int i = 0; i < 2; i++) {
        int s = t + i * 512;
        gload_lds16(src + s * 8, Bsn + s * 8);
      }
    }
    f32x4 acc[2][2];
#pragma unroll
    for (int i = 0; i < 2; i++)
#pragma unroll
      for (int j = 0; j < 2; j++) acc[i][j] = (f32x4){0.f, 0.f, 0.f, 0.f};
#pragma unroll
    for (int ks = 0; ks < 4; ks++) {
      int c = ks * 4 + (l >> 4);
      bf16x8 b[2];
#pragma unroll
      for (int nt = 0; nt < 2; nt++) {
        int rb = wn * 32 + nt * 16 + (l & 15);
        b[nt] = ld8(Bsc + rb * 128 + ((c ^ (rb & 7)) << 3));
      }
#pragma unroll
      for (int mt = 0; mt < 2; mt++) {
        acc[mt][0] = __builtin_amdgcn_mfma_f32_16x16x32_bf16(af[mt][ks], b[0], acc[mt][0], 0, 0, 0);
        acc[mt][1] = __builtin_amdgcn_mfma_f32_16x16x32_bf16(af[mt][ks], b[1], acc[mt][1], 0, 0, 0);
      }
    }
    // ---- epilogue ----
    const int colbase = g * CG + tl * BNT;
    if ((colbase >> 7) == bm) {             // diagonal overlap: s/t pre-exp
#pragma unroll
      for (int mt = 0; mt < 2; mt++)
#pragma unroll
        for (int nt = 0; nt < 2; nt++)
#pragma unroll
          for (int r4 = 0; r4 < 4; r4++) {
            int gr = bm * 128 + wm * 32 + mt * 16 + ((l >> 4) << 2) + r4;
            int gc = colbase + wn * 32 + nt * 16 + (l & 15);
            if (gr == gc) diag[gr] = acc[mt][nt][r4] * invt;
          }
    }
#pragma unroll
    for (int mt = 0; mt < 2; mt++)
#pragma unroll
      for (int nt = 0; nt < 2; nt++) {
        f32x4 y = acc[mt][nt] * kk - kk;    // exp((s-1)/t) = exp2(s*kk - kk)
#pragma unroll
        for (int r4 = 0; r4 < 4; r4++) acc[mt][nt][r4] = __builtin_amdgcn_exp2f(y[r4]);
      }
#pragma unroll
    for (int mt = 0; mt < 2; mt++) racc[mt] += acc[mt][0] + acc[mt][1];
#pragma unroll
    for (int nt = 0; nt < 2; nt++) {        // col partial: 4 lanes/col + LDS atomic
      f32x4 cv = acc[0][nt] + acc[1][nt];
      float cs = (cv[0] + cv[1]) + (cv[2] + cv[3]);
      cs += __shfl_xor(cs, 16); cs += __shfl_xor(cs, 32);
      if (l < 16) atomicAdd(&colred[tl * BNT + wn * 32 + nt * 16 + l], cs);
    }
    __syncthreads();                        // stage(tl+1) drained + Bsc reads done
  }
  // final row reduce across 16 lanes sharing each row
#pragma unroll
  for (int mt = 0; mt < 2; mt++)
#pragma unroll
    for (int r4 = 0; r4 < 4; r4++) {
      float rs = racc[mt][r4];
      rs += __shfl_xor(rs, 1); rs += __shfl_xor(rs, 2);
      rs += __shfl_xor(rs, 4); rs += __shfl_xor(rs, 8);
      if ((l & 15) == 0)
        rowred[wn][wm * 32 + mt * 16 + ((l >> 4) << 2) + r4] = rs;
    }
  __syncthreads();
  if (t < 128)
    rowpart[(size_t)g * NB + bm * 128 + t] = rowred[0][t] + rowred[1][t];
  for (int c = t; c < CG; c += 512)
    colpart[(size_t)bm * NB + g * CG + c] = colred[c];
}

// ---------------------------------------------------------------------------
// K3: fused finalize: per-row reduce -> block atomic -> last block writes out
// ---------------------------------------------------------------------------
__global__ void finalize(const float* __restrict__ rowpart, const float* __restrict__ colpart,
                         const float* __restrict__ diag, const float* __restrict__ log_temp,
                         float* __restrict__ lossacc, float* __restrict__ out) {
  int i = blockIdx.x * 64 + threadIdx.x;
  float rsum = 0.f, csum = 0.f;
#pragma unroll
  for (int g = 0; g < NSPLIT; g++) rsum += rowpart[(size_t)g * NB + i];
#pragma unroll 16
  for (int b = 0; b < 128; b++) csum += colpart[(size_t)b * NB + i];
  float v = 0.5f * (logf(rsum) + logf(csum)) - diag[i];
  for (int m = 1; m < 64; m <<= 1) v += __shfl_xor(v, m);
  if (threadIdx.x == 0) {
    atomicAdd(lossacc, v);
    __threadfence();
    unsigned n = atomicAdd((unsigned*)(lossacc + 1), 1u);
    if (n == gridDim.x - 1) {
      float tot = atomicAdd(lossacc, 0.f);   // coherent read of final sum
      out[0] = tot / (float)NB + __expf(-log_temp[0]);
    }
  }
}

// ---------------------------------------------------------------------------
extern "C" void kernel_launch(void* const* d_in, const int* in_sizes, int n_in,
                              void* d_out, int out_size, void* d_ws, size_t ws_size,
                              hipStream_t stream) {
  const float* img = (const float*)d_in[0];
  const float* num = (const float*)d_in[1];
  const float* Wi1 = (const float*)d_in[2];
  const float* bi1 = (const float*)d_in[3];
  const float* Wi2 = (const float*)d_in[4];
  const float* bi2 = (const float*)d_in[5];
  const float* Wn1 = (const float*)d_in[6];
  const float* bn1 = (const float*)d_in[7];
  const float* Wn2 = (const float*)d_in[8];
  const float* bn2 = (const float*)d_in[9];
  const float* log_temp = (const float*)d_in[10];
  float* out = (float*)d_out;

  char* w = (char*)d_ws;
  // common small regions:
  bf16_t* ipb  = (bf16_t*)(w);                                // 0..4 MB   (swizzled)
  bf16_t* npb  = (bf16_t*)(w + (4u << 20));                   // 4..8 MB   (swizzled)
  float* colpart = (float*)(w + (8u << 20));                  // 8..16 MB

  const size_t need_big = (90ull << 20) + (64ull << 10) + 8;  // ~94.4 MB
  const bool big = ws_size >= need_big;

  bf16_t *imgb, *numb, *Wi1t, *Wn1t, *Wi2t, *Wn2t;
  float *rowpart, *diag, *lossacc;
  if (big) {
    imgb = (bf16_t*)(w + (16u << 20));                        // 16..80 MB (bf16, swizzled)
    numb = (bf16_t*)(w + (80u << 20));                        // 80..88 MB
    Wi1t = (bf16_t*)(w + (88u << 20));                        // 512 KB
    Wn1t = (bf16_t*)(w + (88u << 20) + (512u << 10));         // 64 KB
    Wi2t = (bf16_t*)(w + (88u << 20) + (576u << 10));         // 32 KB
    Wn2t = (bf16_t*)(w + (88u << 20) + (640u << 10));         // 32 KB
    rowpart = (float*)(w + (89u << 20));                      // 1 MB
    diag    = (float*)(w + (90u << 20));                      // 64 KB
    lossacc = (float*)(w + (90u << 20) + (64u << 10));        // 8 B
  } else {
    // compact 17.9 MB layout (proven in R3/R5): weights live at 16 MB during
    // mlp, rowpart overwrites them during logits (lifetimes disjoint).
    imgb = numb = (bf16_t*)w;                                 // unused (PRE=false)
    Wi1t = (bf16_t*)(w + (16u << 20));                        // 512 KB
    Wn1t = (bf16_t*)(w + (16u << 20) + (512u << 10));         // 64 KB
    Wi2t = (bf16_t*)(w + (16u << 20) + (576u << 10));         // 32 KB
    Wn2t = (bf16_t*)(w + (16u << 20) + (640u << 10));         // 32 KB
    rowpart = (float*)(w + (16u << 20));                      // 1 MB (after mlp)
    diag    = (float*)(w + (17u << 20));                      // 64 KB
    lossacc = (float*)(w + (17u << 20) + (64u << 10));        // 8 B
  }

  const int nimg = big ? 4096 : 0, nnum = big ? 512 : 0;
  prep<<<dim3(nimg + nnum + 1280 + 1), 256, 0, stream>>>(
      img, num, Wi1, Wn1, Wi2, Wn2, imgb, numb, Wi1t, Wn1t, Wi2t, Wn2t,
      lossacc, nimg, nnum);
  if (big) {
    mlp_fused<true><<<dim3(1024), 256, 0, stream>>>(
        imgb, numb, img, num, Wi1t, Wn1t, Wi2t, Wn2t,
        bi1, bn1, bi2, bn2, ipb, npb);
  } else {
    mlp_fused<false><<<dim3(1024), 256, 0, stream>>>(
        imgb, numb, img, num, Wi1t, Wn1t, Wi2t, Wn2t,
        bi1, bn1, bi2, bn2, ipb, npb);
  }
  logits_split<<<dim3(128 * NSPLIT), 512, 0, stream>>>(ipb, npb, log_temp,
                                                       rowpart, colpart, diag);
  finalize<<<dim3(NB / 64), 64, 0, stream>>>(rowpart, colpart, diag, log_temp,
                                             lossacc, out);
}

// Round 11
// 356.479 us; speedup vs baseline: 1.1572x; 1.1572x over previous
//
#include <hip/hip_runtime.h>
#include <hip/hip_bf16.h>

typedef __bf16 bf16_t;
typedef __bf16 bf16x8 __attribute__((ext_vector_type(8)));
typedef float f32x4 __attribute__((ext_vector_type(4)));

#define NB 16384
#define NSPLIT 16           // col groups for logits kernel
#define CG (NB / NSPLIT)    // 1024 cols per block
#define BNT 64              // cols per B-subtile
#define NT (CG / BNT)       // 16 B-subtiles per block

__device__ inline bf16x8 ld8(const bf16_t* p) { return *(const bf16x8*)p; }

// direct global->LDS async copy, 16 B/lane (wave-uniform LDS base + lane*16)
__device__ inline void gload_lds16(const bf16_t* g, bf16_t* l) {
  __builtin_amdgcn_global_load_lds(
      (const __attribute__((address_space(1))) unsigned int*)g,
      (__attribute__((address_space(3))) unsigned int*)l, 16, 0, 0);
}

// ---------------------------------------------------------------------------
// K0 "prep": weight transposes fp32 [K][128] -> bf16 [128][K], CHUNK-SWIZZLED
// (k ^ ((n&7)<<3)), + lossacc/counter zero. [HW-proven in R8]
// ---------------------------------------------------------------------------
__global__ void prep(const float* __restrict__ Wi1, const float* __restrict__ Wn1,
                     const float* __restrict__ Wi2, const float* __restrict__ Wn2,
                     bf16_t* __restrict__ Wi1t, bf16_t* __restrict__ Wn1t,
                     bf16_t* __restrict__ Wi2t, bf16_t* __restrict__ Wn2t,
                     float* __restrict__ lossacc) {
  int b = blockIdx.x;
  if (b < 1280) {
    int idx = b * 256 + threadIdx.x;
    if (idx < 262144) { int k = idx >> 7, n = idx & 127;
      Wi1t[n * 2048 + (k ^ ((n & 7) << 3))] = (bf16_t)Wi1[idx]; return; }
    idx -= 262144;
    if (idx < 32768) { int k = idx >> 7, n = idx & 127;
      Wn1t[n * 256 + (k ^ ((n & 7) << 3))] = (bf16_t)Wn1[idx]; return; }
    idx -= 32768;
    if (idx < 16384) { int k = idx >> 7, n = idx & 127;
      Wi2t[n * 128 + (k ^ ((n & 7) << 3))] = (bf16_t)Wi2[idx]; return; }
    idx -= 16384;
    { int k = idx >> 7, n = idx & 127;
      Wn2t[n * 128 + (k ^ ((n & 7) << 3))] = (bf16_t)Wn2[idx]; }
  } else {
    if (threadIdx.x < 2) lossacc[threadIdx.x] = 0.f;   // loss acc + counter
  }
}

// ---------------------------------------------------------------------------
// K1: FUSED mlp1+relu+mlp2+l2norm, DOUBLE-BUFFERED K-loop.
// Blocks 0..511 img (K=2048), 512..1023 num (K=256). BM=32, BN=128, BK=128.
// A staged from fp32 (VGPR convert + swizzled ds_write); B (pre-swizzled
// weights) via global_load_lds linear. Stage(k+1) issued before compute(k),
// ONE barrier per iter -> HBM latency hidden under MFMA+LDS reads.
// LDS = 2*8K (A) + 2*32K (B) = 80KB exactly -> 2 blocks/CU.
// Phase 2: H->As[0], W2->Bs[0], rnorm in As[1]. Out chunk-swizzled per row.
// ---------------------------------------------------------------------------
__global__ __launch_bounds__(256, 2) void mlp_fused(
    const float* __restrict__ imgf, const float* __restrict__ numf,
    const bf16_t* __restrict__ Wi1t, const bf16_t* __restrict__ Wn1t,
    const bf16_t* __restrict__ Wi2t, const bf16_t* __restrict__ Wn2t,
    const float* __restrict__ bi1, const float* __restrict__ bn1,
    const float* __restrict__ bi2, const float* __restrict__ bn2,
    bf16_t* __restrict__ ipb, bf16_t* __restrict__ npb) {
  __shared__ bf16_t As[2][32 * 128];     // 16 KB
  __shared__ bf16_t Bs[2][128 * 128];    // 64 KB
  const int bid = blockIdx.x;
  const bool isnum = bid >= 512;
  const float*  Xf = isnum ? numf : imgf;
  const bf16_t* W1 = isnum ? Wn1t : Wi1t;
  const bf16_t* W2 = isnum ? Wn2t : Wi2t;
  const float* b1  = isnum ? bn1 : bi1;
  const float* b2  = isnum ? bn2 : bi2;
  bf16_t* Out = isnum ? npb : ipb;
  const int K = isnum ? 256 : 2048;
  const int NK = K >> 7;                 // 2 or 16 iterations of BK=128
  const int t = threadIdx.x, l = t & 63, wid = t >> 6;
  const int wm = wid >> 1, wn = wid & 1; // wave tile 16 rows x 64 cols
  const int row0 = (bid & 511) * 32;

  // ---- staging helpers (inlined) ----
  auto stageA = [&](int kk, int buf) {
#pragma unroll
    for (int i = 0; i < 2; i++) {
      int s = t + i * 256;
      int r = s >> 4, c = s & 15;
      const float* src = Xf + (size_t)(row0 + r) * K + kk * 128 + c * 8;
      float4 f0 = *(const float4*)(src);
      float4 f1 = *(const float4*)(src + 4);
      bf16x8 v;
      v[0]=(bf16_t)f0.x; v[1]=(bf16_t)f0.y; v[2]=(bf16_t)f0.z; v[3]=(bf16_t)f0.w;
      v[4]=(bf16_t)f1.x; v[5]=(bf16_t)f1.y; v[6]=(bf16_t)f1.z; v[7]=(bf16_t)f1.w;
      *(bf16x8*)(As[buf] + r * 128 + ((c ^ (r & 7)) << 3)) = v;
    }
  };
  auto stageB = [&](int kk, int buf) {
#pragma unroll
    for (int i = 0; i < 8; i++) {
      int s = t + i * 256;
      gload_lds16(W1 + (size_t)(s >> 4) * K + kk * 128 + (s & 15) * 8,
                  Bs[buf] + s * 8);
    }
  };

  f32x4 acc[4];
#pragma unroll
  for (int j = 0; j < 4; j++) acc[j] = (f32x4){0.f, 0.f, 0.f, 0.f};

  stageA(0, 0);
  stageB(0, 0);
  __syncthreads();                       // buf0 ready

  for (int kk = 0; kk < NK; kk++) {
    const int cur = kk & 1;
    if (kk + 1 < NK) {                   // prefetch next tile into other buffer
      stageA(kk + 1, cur ^ 1);
      stageB(kk + 1, cur ^ 1);
    }
#pragma unroll
    for (int ks = 0; ks < 4; ks++) {
      int r = wm * 16 + (l & 15);
      int c = ks * 4 + (l >> 4);
      bf16x8 a = ld8(As[cur] + r * 128 + ((c ^ (r & 7)) << 3));
#pragma unroll
      for (int nt = 0; nt < 4; nt++) {
        int rb = wn * 64 + nt * 16 + (l & 15);
        bf16x8 bfr = ld8(Bs[cur] + rb * 128 + ((c ^ (rb & 7)) << 3));
        acc[nt] = __builtin_amdgcn_mfma_f32_16x16x32_bf16(a, bfr, acc[nt], 0, 0, 0);
      }
    }
    __syncthreads();   // reads of buf[cur] done + stage(kk+1) drained
  }

  // ---- phase 2: H = relu(acc+b1) -> As[0]; W2 -> Bs[0]; rnorm in As[1] ----
  float* rnorm = (float*)As[1];
#pragma unroll
  for (int i = 0; i < 8; i++) {          // stage W2 (pre-swizzled, linear dest)
    int s = t + i * 256;
    gload_lds16(W2 + (size_t)(s >> 4) * 128 + (s & 15) * 8, Bs[0] + s * 8);
  }
  if (t < 32) rnorm[t] = 0.f;
  {
    int rbase = wm * 16 + ((l >> 4) << 2);
#pragma unroll
    for (int nt = 0; nt < 4; nt++) {
      int col = wn * 64 + nt * 16 + (l & 15);
      float bv = b1[col];
#pragma unroll
      for (int r4 = 0; r4 < 4; r4++) {
        int row = rbase + r4;
        float h = fmaxf(acc[nt][r4] + bv, 0.f);
        As[0][row * 128 + (col ^ ((row & 7) << 3))] = (bf16_t)h;
      }
    }
  }
  __syncthreads();   // H ds_writes + W2 gloads + rnorm init drained

  f32x4 acc2[4];
#pragma unroll
  for (int j = 0; j < 4; j++) acc2[j] = (f32x4){0.f, 0.f, 0.f, 0.f};
#pragma unroll
  for (int ks = 0; ks < 4; ks++) {
    int r = wm * 16 + (l & 15);
    int c = ks * 4 + (l >> 4);
    bf16x8 a = ld8(As[0] + r * 128 + ((c ^ (r & 7)) << 3));
#pragma unroll
    for (int nt = 0; nt < 4; nt++) {
      int rb = wn * 64 + nt * 16 + (l & 15);
      bf16x8 bfr = ld8(Bs[0] + rb * 128 + ((c ^ (rb & 7)) << 3));
      acc2[nt] = __builtin_amdgcn_mfma_f32_16x16x32_bf16(a, bfr, acc2[nt], 0, 0, 0);
    }
  }
  // + bias, l2norm, swizzled store
  float vv[4][4];
#pragma unroll
  for (int nt = 0; nt < 4; nt++) {
    int col = wn * 64 + nt * 16 + (l & 15);
    float bv = b2[col];
#pragma unroll
    for (int r4 = 0; r4 < 4; r4++) vv[nt][r4] = acc2[nt][r4] + bv;
  }
#pragma unroll
  for (int r4 = 0; r4 < 4; r4++) {
    float p = 0.f;
#pragma unroll
    for (int nt = 0; nt < 4; nt++) p += vv[nt][r4] * vv[nt][r4];
    p += __shfl_xor(p, 1); p += __shfl_xor(p, 2);
    p += __shfl_xor(p, 4); p += __shfl_xor(p, 8);
    if ((l & 15) == 0) atomicAdd(&rnorm[wm * 16 + ((l >> 4) << 2) + r4], p);
  }
  __syncthreads();
#pragma unroll
  for (int r4 = 0; r4 < 4; r4++) {
    int rl = wm * 16 + ((l >> 4) << 2) + r4;
    float sc = 1.f / fmaxf(sqrtf(rnorm[rl]), 1e-12f);
#pragma unroll
    for (int nt = 0; nt < 4; nt++) {
      int col = wn * 64 + nt * 16 + (l & 15);
      int swcol = col ^ ((rl & 7) << 3);
      Out[(size_t)(row0 + rl) * 128 + swcol] = (bf16_t)(vv[nt][r4] * sc);
    }
  }
}

// ---------------------------------------------------------------------------
// K2 logits: 512 threads / 8 waves (4 wm x 2 wn, 32x32 per wave).
// Block (bm,g): rows [bm*128,+128) x cols [g*1024,+1024) in 16 subtiles of 64.
// A-frags in registers; 32KB LDS double-buffers B; col sums via LDS atomics.
// launch_bounds(512,4): VGPR cap 128 (R8's (512,6) capped at 40 -> spills,
// 103MB scratch writes). 2 blocks/CU = 16 waves/CU.
// ---------------------------------------------------------------------------
__global__ __launch_bounds__(512, 4) void logits_split(
    const bf16_t* __restrict__ IP, const bf16_t* __restrict__ NP,
    const float* __restrict__ log_temp, float* __restrict__ rowpart,
    float* __restrict__ colpart, float* __restrict__ diag) {
  __shared__ bf16_t BsAll[2 * BNT * 128];  // 32 KB: A staging, then B dbuf
  __shared__ float colred[CG];             // 4 KB, LDS-atomic accumulated
  __shared__ float rowred[2][128];         // 1 KB
  int bid = blockIdx.x;
  int sw = (bid & 7) * (128 * NSPLIT / 8) + (bid >> 3);  // XCD-chunked bijective
  int bm = sw >> 4, g = sw & (NSPLIT - 1);
  const int t = threadIdx.x, l = t & 63, wid = t >> 6;
  const int wm = wid >> 1, wn = wid & 1;   // wave tile 32 rows x 32 cols
  const float invt = __expf(-log_temp[0]);
  const float kk = invt * 1.44269504088896f;   // log2(e)/t

  for (int i = t; i < CG; i += 512) colred[i] = 0.f;
  // stage A (128x128, 32KB) into BsAll; lift frags to regs
#pragma unroll
  for (int i = 0; i < 4; i++) {
    int s = t + i * 512;
    gload_lds16(IP + (size_t)bm * (128 * 128) + s * 8, BsAll + s * 8);
  }
  __syncthreads();
  bf16x8 af[2][4];                          // [mt][ks], 32 VGPR
#pragma unroll
  for (int mt = 0; mt < 2; mt++) {
    int r = wm * 32 + mt * 16 + (l & 15);
#pragma unroll
    for (int ks = 0; ks < 4; ks++) {
      int c = ks * 4 + (l >> 4);
      af[mt][ks] = ld8(BsAll + r * 128 + ((c ^ (r & 7)) << 3));
    }
  }
  __syncthreads();                          // all waves done reading A
#pragma unroll
  for (int i = 0; i < 2; i++) {             // stage B tile 0 into half 0
    int s = t + i * 512;
    gload_lds16(NP + (size_t)(g * CG) * 128 + s * 8, BsAll + s * 8);
  }
  __syncthreads();                          // drains vmcnt: B0 ready

  f32x4 racc[2];
  racc[0] = (f32x4){0.f, 0.f, 0.f, 0.f};
  racc[1] = (f32x4){0.f, 0.f, 0.f, 0.f};

#pragma unroll 1
  for (int tl = 0; tl < NT; tl++) {
    bf16_t* Bsc = BsAll + (tl & 1) * (BNT * 128);
    if (tl + 1 < NT) {                      // async-stage next tile, other half
      bf16_t* Bsn = BsAll + ((tl + 1) & 1) * (BNT * 128);
      const bf16_t* src = NP + (size_t)(g * CG + (tl + 1) * BNT) * 128;
#pragma unroll
      for (int i = 0; i < 2; i++) {
        int s = t + i * 512;
        gload_lds16(src + s * 8, Bsn + s * 8);
      }
    }
    f32x4 acc[2][2];
#pragma unroll
    for (int i = 0; i < 2; i++)
#pragma unroll
      for (int j = 0; j < 2; j++) acc[i][j] = (f32x4){0.f, 0.f, 0.f, 0.f};
#pragma unroll
    for (int ks = 0; ks < 4; ks++) {
      int c = ks * 4 + (l >> 4);
      bf16x8 b[2];
#pragma unroll
      for (int nt = 0; nt < 2; nt++) {
        int rb = wn * 32 + nt * 16 + (l & 15);
        b[nt] = ld8(Bsc + rb * 128 + ((c ^ (rb & 7)) << 3));
      }
#pragma unroll
      for (int mt = 0; mt < 2; mt++) {
        acc[mt][0] = __builtin_amdgcn_mfma_f32_16x16x32_bf16(af[mt][ks], b[0], acc[mt][0], 0, 0, 0);
        acc[mt][1] = __builtin_amdgcn_mfma_f32_16x16x32_bf16(af[mt][ks], b[1], acc[mt][1], 0, 0, 0);
      }
    }
    // ---- epilogue ----
    const int colbase = g * CG + tl * BNT;
    if ((colbase >> 7) == bm) {             // diagonal overlap: s/t pre-exp
#pragma unroll
      for (int mt = 0; mt < 2; mt++)
#pragma unroll
        for (int nt = 0; nt < 2; nt++)
#pragma unroll
          for (int r4 = 0; r4 < 4; r4++) {
            int gr = bm * 128 + wm * 32 + mt * 16 + ((l >> 4) << 2) + r4;
            int gc = colbase + wn * 32 + nt * 16 + (l & 15);
            if (gr == gc) diag[gr] = acc[mt][nt][r4] * invt;
          }
    }
#pragma unroll
    for (int mt = 0; mt < 2; mt++)
#pragma unroll
      for (int nt = 0; nt < 2; nt++) {
        f32x4 y = acc[mt][nt] * kk - kk;    // exp((s-1)/t) = exp2(s*kk - kk)
#pragma unroll
        for (int r4 = 0; r4 < 4; r4++) acc[mt][nt][r4] = __builtin_amdgcn_exp2f(y[r4]);
      }
#pragma unroll
    for (int mt = 0; mt < 2; mt++) racc[mt] += acc[mt][0] + acc[mt][1];
#pragma unroll
    for (int nt = 0; nt < 2; nt++) {        // col partial: 4 lanes/col + LDS atomic
      f32x4 cv = acc[0][nt] + acc[1][nt];
      float cs = (cv[0] + cv[1]) + (cv[2] + cv[3]);
      cs += __shfl_xor(cs, 16); cs += __shfl_xor(cs, 32);
      if (l < 16) atomicAdd(&colred[tl * BNT + wn * 32 + nt * 16 + l], cs);
    }
    __syncthreads();                        // stage(tl+1) drained + Bsc reads done
  }
  // final row reduce across 16 lanes sharing each row
#pragma unroll
  for (int mt = 0; mt < 2; mt++)
#pragma unroll
    for (int r4 = 0; r4 < 4; r4++) {
      float rs = racc[mt][r4];
      rs += __shfl_xor(rs, 1); rs += __shfl_xor(rs, 2);
      rs += __shfl_xor(rs, 4); rs += __shfl_xor(rs, 8);
      if ((l & 15) == 0)
        rowred[wn][wm * 32 + mt * 16 + ((l >> 4) << 2) + r4] = rs;
    }
  __syncthreads();
  if (t < 128)
    rowpart[(size_t)g * NB + bm * 128 + t] = rowred[0][t] + rowred[1][t];
  for (int c = t; c < CG; c += 512)
    colpart[(size_t)bm * NB + g * CG + c] = colred[c];
}

// ---------------------------------------------------------------------------
// K3: fused finalize: per-row reduce -> block atomic -> last block writes out
// ---------------------------------------------------------------------------
__global__ void finalize(const float* __restrict__ rowpart, const float* __restrict__ colpart,
                         const float* __restrict__ diag, const float* __restrict__ log_temp,
                         float* __restrict__ lossacc, float* __restrict__ out) {
  int i = blockIdx.x * 64 + threadIdx.x;
  float rsum = 0.f, csum = 0.f;
#pragma unroll
  for (int g = 0; g < NSPLIT; g++) rsum += rowpart[(size_t)g * NB + i];
#pragma unroll 16
  for (int b = 0; b < 128; b++) csum += colpart[(size_t)b * NB + i];
  float v = 0.5f * (logf(rsum) + logf(csum)) - diag[i];
  for (int m = 1; m < 64; m <<= 1) v += __shfl_xor(v, m);
  if (threadIdx.x == 0) {
    atomicAdd(lossacc, v);
    __threadfence();
    unsigned n = atomicAdd((unsigned*)(lossacc + 1), 1u);
    if (n == gridDim.x - 1) {
      float tot = atomicAdd(lossacc, 0.f);   // coherent read of final sum
      out[0] = tot / (float)NB + __expf(-log_temp[0]);
    }
  }
}

// ---------------------------------------------------------------------------
extern "C" void kernel_launch(void* const* d_in, const int* in_sizes, int n_in,
                              void* d_out, int out_size, void* d_ws, size_t ws_size,
                              hipStream_t stream) {
  const float* img = (const float*)d_in[0];
  const float* num = (const float*)d_in[1];
  const float* Wi1 = (const float*)d_in[2];
  const float* bi1 = (const float*)d_in[3];
  const float* Wi2 = (const float*)d_in[4];
  const float* bi2 = (const float*)d_in[5];
  const float* Wn1 = (const float*)d_in[6];
  const float* bn1 = (const float*)d_in[7];
  const float* Wn2 = (const float*)d_in[8];
  const float* bn2 = (const float*)d_in[9];
  const float* log_temp = (const float*)d_in[10];
  float* out = (float*)d_out;

  // compact 17.9 MB workspace layout (HW-proven):
  char* w = (char*)d_ws;
  bf16_t* ipb  = (bf16_t*)(w);                                // 0..4 MB   (swizzled)
  bf16_t* npb  = (bf16_t*)(w + (4u << 20));                   // 4..8 MB   (swizzled)
  float* colpart = (float*)(w + (8u << 20));                  // 8..16 MB
  bf16_t* Wi1t = (bf16_t*)(w + (16u << 20));                  // 512 KB (mlp lifetime)
  bf16_t* Wn1t = (bf16_t*)(w + (16u << 20) + (512u << 10));   // 64 KB
  bf16_t* Wi2t = (bf16_t*)(w + (16u << 20) + (576u << 10));   // 32 KB
  bf16_t* Wn2t = (bf16_t*)(w + (16u << 20) + (640u << 10));   // 32 KB
  float* rowpart = (float*)(w + (16u << 20));                 // 1 MB (logits lifetime)
  float* diag    = (float*)(w + (17u << 20));                 // 64 KB
  float* lossacc = (float*)(w + (17u << 20) + (64u << 10));   // 8 B (acc + counter)

  prep<<<dim3(1281), 256, 0, stream>>>(Wi1, Wn1, Wi2, Wn2,
                                       Wi1t, Wn1t, Wi2t, Wn2t, lossacc);
  mlp_fused<<<dim3(1024), 256, 0, stream>>>(img, num, Wi1t, Wn1t, Wi2t, Wn2t,
                                            bi1, bn1, bi2, bn2, ipb, npb);
  logits_split<<<dim3(128 * NSPLIT), 512, 0, stream>>>(ipb, npb, log_temp,
                                                       rowpart, colpart, diag);
  finalize<<<dim3(NB / 64), 64, 0, stream>>>(rowpart, colpart, diag, log_temp,
                                             lossacc, out);
}

// Round 12
// 337.878 us; speedup vs baseline: 1.2209x; 1.0551x over previous
//
#include <hip/hip_runtime.h>
#include <hip/hip_bf16.h>

typedef __bf16 bf16_t;
typedef __bf16 bf16x8 __attribute__((ext_vector_type(8)));
typedef float f32x4 __attribute__((ext_vector_type(4)));

#define NB 16384
#define NSPLIT 16           // col groups for logits kernel
#define CG (NB / NSPLIT)    // 1024 cols per block
#define BNT 64              // cols per B-subtile
#define NT (CG / BNT)       // 16 B-subtiles per block

__device__ inline bf16x8 ld8(const bf16_t* p) { return *(const bf16x8*)p; }

// direct global->LDS async copy, 16 B/lane (wave-uniform LDS base + lane*16)
__device__ inline void gload_lds16(const bf16_t* g, bf16_t* l) {
  __builtin_amdgcn_global_load_lds(
      (const __attribute__((address_space(1))) unsigned int*)g,
      (__attribute__((address_space(3))) unsigned int*)l, 16, 0, 0);
}

// ---------------------------------------------------------------------------
// K0 "prep": weight transposes fp32 [K][128] -> bf16 [128][K], CHUNK-SWIZZLED
// (k ^ ((n&7)<<3)), + lossacc/counter zero. [HW-proven R8/R11]
// ---------------------------------------------------------------------------
__global__ void prep(const float* __restrict__ Wi1, const float* __restrict__ Wn1,
                     const float* __restrict__ Wi2, const float* __restrict__ Wn2,
                     bf16_t* __restrict__ Wi1t, bf16_t* __restrict__ Wn1t,
                     bf16_t* __restrict__ Wi2t, bf16_t* __restrict__ Wn2t,
                     float* __restrict__ lossacc) {
  int b = blockIdx.x;
  if (b < 1280) {
    int idx = b * 256 + threadIdx.x;
    if (idx < 262144) { int k = idx >> 7, n = idx & 127;
      Wi1t[n * 2048 + (k ^ ((n & 7) << 3))] = (bf16_t)Wi1[idx]; return; }
    idx -= 262144;
    if (idx < 32768) { int k = idx >> 7, n = idx & 127;
      Wn1t[n * 256 + (k ^ ((n & 7) << 3))] = (bf16_t)Wn1[idx]; return; }
    idx -= 32768;
    if (idx < 16384) { int k = idx >> 7, n = idx & 127;
      Wi2t[n * 128 + (k ^ ((n & 7) << 3))] = (bf16_t)Wi2[idx]; return; }
    idx -= 16384;
    { int k = idx >> 7, n = idx & 127;
      Wn2t[n * 128 + (k ^ ((n & 7) << 3))] = (bf16_t)Wn2[idx]; }
  } else {
    if (threadIdx.x < 2) lossacc[threadIdx.x] = 0.f;   // loss acc + counter
  }
}

// ---------------------------------------------------------------------------
// K1: one MLP path (mlp1+relu+mlp2+l2norm), DOUBLE-BUFFERED K-loop.
// Identical per-block code to R11's mlp_fused; img and num are now SEPARATE
// launches (512 blocks each) so each gets its own profiler row.
// BM=32, BN=128, BK=128. LDS = 2*8K + 2*32K = 80KB -> 2 blocks/CU.
// ---------------------------------------------------------------------------
__global__ __launch_bounds__(256, 2) void mlp_path(
    const float* __restrict__ Xf, const bf16_t* __restrict__ W1,
    const bf16_t* __restrict__ W2, const float* __restrict__ b1,
    const float* __restrict__ b2, bf16_t* __restrict__ Out, int K) {
  __shared__ bf16_t As[2][32 * 128];     // 16 KB
  __shared__ bf16_t Bs[2][128 * 128];    // 64 KB
  const int NK = K >> 7;                 // 2 or 16 iterations of BK=128
  const int t = threadIdx.x, l = t & 63, wid = t >> 6;
  const int wm = wid >> 1, wn = wid & 1; // wave tile 16 rows x 64 cols
  const int row0 = blockIdx.x * 32;

  auto stageA = [&](int kk, int buf) {
#pragma unroll
    for (int i = 0; i < 2; i++) {
      int s = t + i * 256;
      int r = s >> 4, c = s & 15;
      const float* src = Xf + (size_t)(row0 + r) * K + kk * 128 + c * 8;
      float4 f0 = *(const float4*)(src);
      float4 f1 = *(const float4*)(src + 4);
      bf16x8 v;
      v[0]=(bf16_t)f0.x; v[1]=(bf16_t)f0.y; v[2]=(bf16_t)f0.z; v[3]=(bf16_t)f0.w;
      v[4]=(bf16_t)f1.x; v[5]=(bf16_t)f1.y; v[6]=(bf16_t)f1.z; v[7]=(bf16_t)f1.w;
      *(bf16x8*)(As[buf] + r * 128 + ((c ^ (r & 7)) << 3)) = v;
    }
  };
  auto stageB = [&](int kk, int buf) {
#pragma unroll
    for (int i = 0; i < 8; i++) {
      int s = t + i * 256;
      gload_lds16(W1 + (size_t)(s >> 4) * K + kk * 128 + (s & 15) * 8,
                  Bs[buf] + s * 8);
    }
  };

  f32x4 acc[4];
#pragma unroll
  for (int j = 0; j < 4; j++) acc[j] = (f32x4){0.f, 0.f, 0.f, 0.f};

  stageA(0, 0);
  stageB(0, 0);
  __syncthreads();                       // buf0 ready

  for (int kk = 0; kk < NK; kk++) {
    const int cur = kk & 1;
    if (kk + 1 < NK) {                   // prefetch next tile into other buffer
      stageA(kk + 1, cur ^ 1);
      stageB(kk + 1, cur ^ 1);
    }
#pragma unroll
    for (int ks = 0; ks < 4; ks++) {
      int r = wm * 16 + (l & 15);
      int c = ks * 4 + (l >> 4);
      bf16x8 a = ld8(As[cur] + r * 128 + ((c ^ (r & 7)) << 3));
#pragma unroll
      for (int nt = 0; nt < 4; nt++) {
        int rb = wn * 64 + nt * 16 + (l & 15);
        bf16x8 bfr = ld8(Bs[cur] + rb * 128 + ((c ^ (rb & 7)) << 3));
        acc[nt] = __builtin_amdgcn_mfma_f32_16x16x32_bf16(a, bfr, acc[nt], 0, 0, 0);
      }
    }
    __syncthreads();   // reads of buf[cur] done + stage(kk+1) drained
  }

  // ---- phase 2: H = relu(acc+b1) -> As[0]; W2 -> Bs[0]; rnorm in As[1] ----
  float* rnorm = (float*)As[1];
#pragma unroll
  for (int i = 0; i < 8; i++) {          // stage W2 (pre-swizzled, linear dest)
    int s = t + i * 256;
    gload_lds16(W2 + (size_t)(s >> 4) * 128 + (s & 15) * 8, Bs[0] + s * 8);
  }
  if (t < 32) rnorm[t] = 0.f;
  {
    int rbase = wm * 16 + ((l >> 4) << 2);
#pragma unroll
    for (int nt = 0; nt < 4; nt++) {
      int col = wn * 64 + nt * 16 + (l & 15);
      float bv = b1[col];
#pragma unroll
      for (int r4 = 0; r4 < 4; r4++) {
        int row = rbase + r4;
        float h = fmaxf(acc[nt][r4] + bv, 0.f);
        As[0][row * 128 + (col ^ ((row & 7) << 3))] = (bf16_t)h;
      }
    }
  }
  __syncthreads();   // H ds_writes + W2 gloads + rnorm init drained

  f32x4 acc2[4];
#pragma unroll
  for (int j = 0; j < 4; j++) acc2[j] = (f32x4){0.f, 0.f, 0.f, 0.f};
#pragma unroll
  for (int ks = 0; ks < 4; ks++) {
    int r = wm * 16 + (l & 15);
    int c = ks * 4 + (l >> 4);
    bf16x8 a = ld8(As[0] + r * 128 + ((c ^ (r & 7)) << 3));
#pragma unroll
    for (int nt = 0; nt < 4; nt++) {
      int rb = wn * 64 + nt * 16 + (l & 15);
      bf16x8 bfr = ld8(Bs[0] + rb * 128 + ((c ^ (rb & 7)) << 3));
      acc2[nt] = __builtin_amdgcn_mfma_f32_16x16x32_bf16(a, bfr, acc2[nt], 0, 0, 0);
    }
  }
  float vv[4][4];
#pragma unroll
  for (int nt = 0; nt < 4; nt++) {
    int col = wn * 64 + nt * 16 + (l & 15);
    float bv = b2[col];
#pragma unroll
    for (int r4 = 0; r4 < 4; r4++) vv[nt][r4] = acc2[nt][r4] + bv;
  }
#pragma unroll
  for (int r4 = 0; r4 < 4; r4++) {
    float p = 0.f;
#pragma unroll
    for (int nt = 0; nt < 4; nt++) p += vv[nt][r4] * vv[nt][r4];
    p += __shfl_xor(p, 1); p += __shfl_xor(p, 2);
    p += __shfl_xor(p, 4); p += __shfl_xor(p, 8);
    if ((l & 15) == 0) atomicAdd(&rnorm[wm * 16 + ((l >> 4) << 2) + r4], p);
  }
  __syncthreads();
#pragma unroll
  for (int r4 = 0; r4 < 4; r4++) {
    int rl = wm * 16 + ((l >> 4) << 2) + r4;
    float sc = 1.f / fmaxf(sqrtf(rnorm[rl]), 1e-12f);
#pragma unroll
    for (int nt = 0; nt < 4; nt++) {
      int col = wn * 64 + nt * 16 + (l & 15);
      int swcol = col ^ ((rl & 7) << 3);
      Out[(size_t)(row0 + rl) * 128 + swcol] = (bf16_t)(vv[nt][r4] * sc);
    }
  }
}

// ---------------------------------------------------------------------------
// K2 logits: REVERT to R5-measured config (105 us): 256 thr / 4 waves
// (2 wm x 2 wn, 64x32 per wave), af[4][4] in regs, 32 MFMA per barrier,
// BNT=64 dbuf via gload_lds. Only delta vs R5: colred is single-buffer
// LDS-atomic (R11-validated numerically). LDS ~37KB.
// ---------------------------------------------------------------------------
__global__ __launch_bounds__(256, 3) void logits_split(
    const bf16_t* __restrict__ IP, const bf16_t* __restrict__ NP,
    const float* __restrict__ log_temp, float* __restrict__ rowpart,
    float* __restrict__ colpart, float* __restrict__ diag) {
  __shared__ bf16_t BsAll[2 * BNT * 128];  // 32 KB: A staging, then B dbuf
  __shared__ float colred[CG];             // 4 KB, LDS-atomic accumulated
  __shared__ float rowred[2][128];         // 1 KB
  int bid = blockIdx.x;
  int sw = (bid & 7) * (128 * NSPLIT / 8) + (bid >> 3);  // XCD-chunked bijective
  int bm = sw >> 4, g = sw & (NSPLIT - 1);
  const int t = threadIdx.x, l = t & 63, wid = t >> 6;
  const int wm = wid >> 1, wn = wid & 1;   // wave tile 64 rows x 32 cols
  const float invt = __expf(-log_temp[0]);
  const float kk = invt * 1.44269504088896f;   // log2(e)/t

  for (int i = t; i < CG; i += 256) colred[i] = 0.f;
  // stage A (128x128, 32KB) into BsAll; lift frags to regs
#pragma unroll
  for (int i = 0; i < 8; i++) {
    int s = t + i * 256;
    gload_lds16(IP + (size_t)bm * (128 * 128) + s * 8, BsAll + s * 8);
  }
  __syncthreads();
  bf16x8 af[4][4];                          // [mt][ks], 64 VGPR
#pragma unroll
  for (int mt = 0; mt < 4; mt++) {
    int r = wm * 64 + mt * 16 + (l & 15);
#pragma unroll
    for (int ks = 0; ks < 4; ks++) {
      int c = ks * 4 + (l >> 4);
      af[mt][ks] = ld8(BsAll + r * 128 + ((c ^ (r & 7)) << 3));
    }
  }
  __syncthreads();                          // all waves done reading A
#pragma unroll
  for (int i = 0; i < 4; i++) {             // stage B tile 0 into half 0
    int s = t + i * 256;
    gload_lds16(NP + (size_t)(g * CG) * 128 + s * 8, BsAll + s * 8);
  }
  __syncthreads();                          // drains vmcnt: B0 ready

  f32x4 racc[4];
#pragma unroll
  for (int a = 0; a < 4; a++) racc[a] = (f32x4){0.f, 0.f, 0.f, 0.f};

#pragma unroll 1
  for (int tl = 0; tl < NT; tl++) {
    bf16_t* Bsc = BsAll + (tl & 1) * (BNT * 128);
    if (tl + 1 < NT) {                      // async-stage next tile, other half
      bf16_t* Bsn = BsAll + ((tl + 1) & 1) * (BNT * 128);
      const bf16_t* src = NP + (size_t)(g * CG + (tl + 1) * BNT) * 128;
#pragma unroll
      for (int i = 0; i < 4; i++) {
        int s = t + i * 256;
        gload_lds16(src + s * 8, Bsn + s * 8);
      }
    }
    f32x4 acc[4][2];
#pragma unroll
    for (int i = 0; i < 4; i++)
#pragma unroll
      for (int j = 0; j < 2; j++) acc[i][j] = (f32x4){0.f, 0.f, 0.f, 0.f};
#pragma unroll
    for (int ks = 0; ks < 4; ks++) {
      int c = ks * 4 + (l >> 4);
      bf16x8 b[2];
#pragma unroll
      for (int nt = 0; nt < 2; nt++) {
        int rb = wn * 32 + nt * 16 + (l & 15);
        b[nt] = ld8(Bsc + rb * 128 + ((c ^ (rb & 7)) << 3));
      }
#pragma unroll
      for (int mt = 0; mt < 4; mt++) {
        acc[mt][0] = __builtin_amdgcn_mfma_f32_16x16x32_bf16(af[mt][ks], b[0], acc[mt][0], 0, 0, 0);
        acc[mt][1] = __builtin_amdgcn_mfma_f32_16x16x32_bf16(af[mt][ks], b[1], acc[mt][1], 0, 0, 0);
      }
    }
    // ---- epilogue ----
    const int colbase = g * CG + tl * BNT;
    if ((colbase >> 7) == bm) {             // diagonal overlap: s/t pre-exp
#pragma unroll
      for (int mt = 0; mt < 4; mt++)
#pragma unroll
        for (int nt = 0; nt < 2; nt++)
#pragma unroll
          for (int r4 = 0; r4 < 4; r4++) {
            int gr = bm * 128 + wm * 64 + mt * 16 + ((l >> 4) << 2) + r4;
            int gc = colbase + wn * 32 + nt * 16 + (l & 15);
            if (gr == gc) diag[gr] = acc[mt][nt][r4] * invt;
          }
    }
#pragma unroll
    for (int mt = 0; mt < 4; mt++)
#pragma unroll
      for (int nt = 0; nt < 2; nt++) {
        f32x4 y = acc[mt][nt] * kk - kk;    // exp((s-1)/t) = exp2(s*kk - kk)
#pragma unroll
        for (int r4 = 0; r4 < 4; r4++) acc[mt][nt][r4] = __builtin_amdgcn_exp2f(y[r4]);
      }
#pragma unroll
    for (int mt = 0; mt < 4; mt++) racc[mt] += acc[mt][0] + acc[mt][1];
#pragma unroll
    for (int nt = 0; nt < 2; nt++) {        // col partial: 4 lanes/col + LDS atomic
      f32x4 cv = (acc[0][nt] + acc[1][nt]) + (acc[2][nt] + acc[3][nt]);
      float cs = (cv[0] + cv[1]) + (cv[2] + cv[3]);
      cs += __shfl_xor(cs, 16); cs += __shfl_xor(cs, 32);
      if (l < 16) atomicAdd(&colred[tl * BNT + wn * 32 + nt * 16 + l], cs);
    }
    __syncthreads();                        // stage(tl+1) drained + Bsc reads done
  }
  // final row reduce across 16 lanes sharing each row
#pragma unroll
  for (int mt = 0; mt < 4; mt++)
#pragma unroll
    for (int r4 = 0; r4 < 4; r4++) {
      float rs = racc[mt][r4];
      rs += __shfl_xor(rs, 1); rs += __shfl_xor(rs, 2);
      rs += __shfl_xor(rs, 4); rs += __shfl_xor(rs, 8);
      if ((l & 15) == 0)
        rowred[wn][wm * 64 + mt * 16 + ((l >> 4) << 2) + r4] = rs;
    }
  __syncthreads();
  if (t < 128)
    rowpart[(size_t)g * NB + bm * 128 + t] = rowred[0][t] + rowred[1][t];
  for (int c = t; c < CG; c += 256)
    colpart[(size_t)bm * NB + g * CG + c] = colred[c];
}

// ---------------------------------------------------------------------------
// K3a: colsum[i] = sum_b colpart[b][i]  (8 MB read, coalesced)
// ---------------------------------------------------------------------------
__global__ void colsum_k(const float* __restrict__ colpart, float* __restrict__ colsum) {
  int i = blockIdx.x * 256 + threadIdx.x;
  float s = 0.f;
#pragma unroll 16
  for (int b = 0; b < 128; b++) s += colpart[(size_t)b * NB + i];
  colsum[i] = s;
}

// ---------------------------------------------------------------------------
// K3b: loss = mean over i of 0.5*(log rsum + log colsum) - diag; +1/t
// ---------------------------------------------------------------------------
__global__ void loss_k(const float* __restrict__ rowpart, const float* __restrict__ colsum,
                       const float* __restrict__ diag, const float* __restrict__ log_temp,
                       float* __restrict__ lossacc, float* __restrict__ out) {
  int i = blockIdx.x * 64 + threadIdx.x;
  float rsum = 0.f;
#pragma unroll
  for (int g = 0; g < NSPLIT; g++) rsum += rowpart[(size_t)g * NB + i];
  float v = 0.5f * (logf(rsum) + logf(colsum[i])) - diag[i];
  for (int m = 1; m < 64; m <<= 1) v += __shfl_xor(v, m);
  if (threadIdx.x == 0) {
    atomicAdd(lossacc, v);
    __threadfence();
    unsigned n = atomicAdd((unsigned*)(lossacc + 1), 1u);
    if (n == gridDim.x - 1) {
      float tot = atomicAdd(lossacc, 0.f);   // coherent read of final sum
      out[0] = tot / (float)NB + __expf(-log_temp[0]);
    }
  }
}

// ---------------------------------------------------------------------------
extern "C" void kernel_launch(void* const* d_in, const int* in_sizes, int n_in,
                              void* d_out, int out_size, void* d_ws, size_t ws_size,
                              hipStream_t stream) {
  const float* img = (const float*)d_in[0];
  const float* num = (const float*)d_in[1];
  const float* Wi1 = (const float*)d_in[2];
  const float* bi1 = (const float*)d_in[3];
  const float* Wi2 = (const float*)d_in[4];
  const float* bi2 = (const float*)d_in[5];
  const float* Wn1 = (const float*)d_in[6];
  const float* bn1 = (const float*)d_in[7];
  const float* Wn2 = (const float*)d_in[8];
  const float* bn2 = (const float*)d_in[9];
  const float* log_temp = (const float*)d_in[10];
  float* out = (float*)d_out;

  // compact workspace layout (<= 17.2 MB, within HW-proven extent):
  char* w = (char*)d_ws;
  bf16_t* ipb  = (bf16_t*)(w);                                // 0..4 MB   (swizzled)
  bf16_t* npb  = (bf16_t*)(w + (4u << 20));                   // 4..8 MB   (swizzled)
  float* colpart = (float*)(w + (8u << 20));                  // 8..16 MB
  bf16_t* Wi1t = (bf16_t*)(w + (16u << 20));                  // 512 KB (mlp lifetime)
  bf16_t* Wn1t = (bf16_t*)(w + (16u << 20) + (512u << 10));   // 64 KB
  bf16_t* Wi2t = (bf16_t*)(w + (16u << 20) + (576u << 10));   // 32 KB
  bf16_t* Wn2t = (bf16_t*)(w + (16u << 20) + (640u << 10));   // 32 KB
  float* rowpart = (float*)(w + (16u << 20));                 // 1 MB (logits lifetime)
  float* diag    = (float*)(w + (17u << 20));                 // 64 KB
  float* colsum  = (float*)(w + (17u << 20) + (64u << 10));   // 64 KB
  float* lossacc = (float*)(w + (17u << 20) + (128u << 10));  // 8 B (acc + counter)

  prep<<<dim3(1281), 256, 0, stream>>>(Wi1, Wn1, Wi2, Wn2,
                                       Wi1t, Wn1t, Wi2t, Wn2t, lossacc);
  mlp_path<<<dim3(512), 256, 0, stream>>>(img, Wi1t, Wi2t, bi1, bi2, ipb, 2048);
  mlp_path<<<dim3(512), 256, 0, stream>>>(num, Wn1t, Wn2t, bn1, bn2, npb, 256);
  logits_split<<<dim3(128 * NSPLIT), 256, 0, stream>>>(ipb, npb, log_temp,
                                                       rowpart, colpart, diag);
  colsum_k<<<dim3(NB / 256), 256, 0, stream>>>(colpart, colsum);
  loss_k<<<dim3(NB / 64), 64, 0, stream>>>(rowpart, colsum, diag, log_temp,
                                           lossacc, out);
}